// Round 10
// baseline (635.074 us; speedup 1.0000x reference)
//
#include <hip/hip_runtime.h>

// ---------------------------------------------------------------------------
// Spectral conv: out = irfft2( rfft2(x) * (w_real + i*w_imag) )
// B=16, C=64, H=256, W=256, WF=129.
//
// Pipeline (spectrum in-place in d_out; d_ws holds transposed weights):
//   K0: weight transpose -> wt[c][wf][h] float2.
//   K1: row r2c FFT-256, TWO row-pair FFTs per wave (dual ping-pong: half the
//       sync phases per FFT, shared twiddles), packed rows.
//   K2: register-column FFT: 256=16x16 four-step, 16-lane group per packed
//       column-pair, one LDS transpose per FFT, multiply in registers.
//   K3: row c2r, dual-FFT per wave like K1.
// ---------------------------------------------------------------------------

// XOR bank swizzle for the Stockham kernels: bijective on [0,256), conflict-
// free for all stage patterns (Ns=1,4,16,64).
#define PHX(i) ((i) ^ ((i) >> 2))

typedef float fvec4 __attribute__((ext_vector_type(4)));

__device__ __forceinline__ float4 nt_load4(const float* p) {
    fvec4 v = __builtin_nontemporal_load((const fvec4*)p);
    return make_float4(v.x, v.y, v.z, v.w);
}
__device__ __forceinline__ void nt_store4(float* p, float4 v) {
    fvec4 t;
    t.x = v.x; t.y = v.y; t.z = v.z; t.w = v.w;
    __builtin_nontemporal_store(t, (fvec4*)p);
}

__device__ __forceinline__ float2 cmulf(float2 a, float2 b) {
    return make_float2(fmaf(a.x, b.x, -a.y * b.y), fmaf(a.x, b.y, a.y * b.x));
}
__device__ __forceinline__ float2 cadd(float2 a, float2 b){ return make_float2(a.x+b.x, a.y+b.y); }
__device__ __forceinline__ float2 csub(float2 a, float2 b){ return make_float2(a.x-b.x, a.y-b.y); }
__device__ __forceinline__ float2 mulmi(float2 a){ return make_float2(a.y, -a.x); }   // *(-i)
__device__ __forceinline__ float2 mulpi(float2 a){ return make_float2(-a.y, a.x); }   // *(+i)

__device__ __forceinline__ void wave_sync() {
    asm volatile("s_waitcnt lgkmcnt(0)" ::: "memory");
    __builtin_amdgcn_wave_barrier();
}

// ======================= register FFT pieces (K2) ==========================

template<int DIR>
__device__ __forceinline__ void dft4(float2 x0, float2 x1, float2 x2, float2 x3,
                                     float2& y0, float2& y1, float2& y2, float2& y3)
{
    float2 s0 = cadd(x0, x2), d0 = csub(x0, x2);
    float2 s1 = cadd(x1, x3), d1 = csub(x1, x3);
    y0 = cadd(s0, s1);
    y2 = csub(s0, s1);
    float2 jd1 = (DIR < 0) ? mulmi(d1) : mulpi(d1);
    y1 = cadd(d0, jd1);
    y3 = csub(d0, jd1);
}

template<int DIR>
__device__ __forceinline__ float2 twd(float2 a, float wr, float wi) {
    return cmulf(a, make_float2(wr, (DIR < 0) ? wi : -wi));
}

template<int DIR>
__device__ __forceinline__ void dft16(float2 v[16])
{
    const float C1 = 0.92387953251128674f;
    const float S1 = 0.38268343236508978f;
    const float R  = 0.70710678118654752f;
    float2 a0, a1, a2, a3;
    dft4<DIR>(v[0], v[4], v[8],  v[12], a0, a1, a2, a3);
    float2 u00 = a0, u01 = a1, u02 = a2, u03 = a3;
    dft4<DIR>(v[1], v[5], v[9],  v[13], a0, a1, a2, a3);
    float2 u10 = a0;
    float2 u11 = twd<DIR>(a1,  C1, -S1);
    float2 u12 = twd<DIR>(a2,   R,  -R);
    float2 u13 = twd<DIR>(a3,  S1, -C1);
    dft4<DIR>(v[2], v[6], v[10], v[14], a0, a1, a2, a3);
    float2 u20 = a0;
    float2 u21 = twd<DIR>(a1,   R,  -R);
    float2 u22 = (DIR < 0) ? mulmi(a2) : mulpi(a2);
    float2 u23 = twd<DIR>(a3,  -R,  -R);
    dft4<DIR>(v[3], v[7], v[11], v[15], a0, a1, a2, a3);
    float2 u30 = a0;
    float2 u31 = twd<DIR>(a1,  S1, -C1);
    float2 u32 = twd<DIR>(a2,  -R,  -R);
    float2 u33 = twd<DIR>(a3, -C1,  S1);
    dft4<DIR>(u00, u10, u20, u30, v[0], v[4], v[8],  v[12]);
    dft4<DIR>(u01, u11, u21, u31, v[1], v[5], v[9],  v[13]);
    dft4<DIR>(u02, u12, u22, u32, v[2], v[6], v[10], v[14]);
    dft4<DIR>(u03, u13, u23, u33, v[3], v[7], v[11], v[15]);
}

template<int DIR>
__device__ __forceinline__ void midtw(float2 v[16], int n2)
{
    float th = ((DIR < 0) ? -6.283185307179586f : 6.283185307179586f)
               * (float)n2 * (1.0f / 256.0f);
    float s, c;
    __sincosf(th, &s, &c);
    float2 base = make_float2(c, s);
    float2 w = base;
    v[1] = cmulf(v[1], w);
#pragma unroll
    for (int k = 2; k < 16; ++k) { w = cmulf(w, base); v[k] = cmulf(v[k], w); }
}

template<int DIR>
__device__ __forceinline__ void gfft(float2 v[16], float2* Ag, int l)
{
    dft16<DIR>(v);
    midtw<DIR>(v, l);
    wave_sync();
#pragma unroll
    for (int k = 0; k < 16; ++k) Ag[l * 17 + k] = v[k];
    wave_sync();
#pragma unroll
    for (int n = 0; n < 16; ++n) v[n] = Ag[n * 17 + l];
    dft16<DIR>(v);
}

// ===================== Stockham pieces (K1/K3) =============================

struct Tw {
    float2 a1, a2, a3;   // Ns=4
    float2 b1, b2, b3;   // Ns=16
    float2 c1, c2, c3;   // Ns=64
};

__device__ __forceinline__ void tw_one(int lane, int Ns, float2& w1, float2& w2, float2& w3) {
    int r = lane & (Ns - 1);
    float th = -6.283185307179586f * (float)r / (float)(4 * Ns);
    float s1, c1;
    __sincosf(th, &s1, &c1);
    w1 = make_float2(c1, s1);
    w2 = make_float2(c1 * c1 - s1 * s1, 2.0f * c1 * s1);
    w3 = make_float2(w2.x * c1 - w2.y * s1, w2.y * c1 + w2.x * s1);
}

__device__ __forceinline__ Tw make_tw(int lane) {
    Tw t;
    tw_one(lane, 4,  t.a1, t.a2, t.a3);
    tw_one(lane, 16, t.b1, t.b2, t.b3);
    tw_one(lane, 64, t.c1, t.c2, t.c3);
    return t;
}

// one butterfly on preloaded values
template<int NS, int DIR>
__device__ __forceinline__ void bfly(float2 v0, float2 v1, float2 v2, float2 v3,
                                     float2* d, int j,
                                     float2 w1, float2 w2, float2 w3)
{
    if (NS > 1) {
        v1 = cmulf(v1, w1);
        v2 = cmulf(v2, w2);
        v3 = cmulf(v3, w3);
    }
    float t0x = v0.x + v2.x, t0y = v0.y + v2.y;
    float t1x = v0.x - v2.x, t1y = v0.y - v2.y;
    float t2x = v1.x + v3.x, t2y = v1.y + v3.y;
    float t3x = v1.x - v3.x, t3y = v1.y - v3.y;
    float ix = (DIR < 0) ? t3y : -t3y;
    float iy = (DIR < 0) ? -t3x : t3x;
    int r = j & (NS - 1);
    int base = ((j & ~(NS - 1)) << 2) | r;
    d[PHX(base)]          = make_float2(t0x + t2x, t0y + t2y);
    d[PHX(base + NS)]     = make_float2(t1x + ix, t1y + iy);
    d[PHX(base + 2*NS)]   = make_float2(t0x - t2x, t0y - t2y);
    d[PHX(base + 3*NS)]   = make_float2(t1x - ix, t1y - iy);
}

// dual-FFT stage: both FFTs' loads issued together, shared twiddles
template<int NS, int DIR>
__device__ __forceinline__ void stage2(const float2* sa, const float2* sb,
                                       float2* da, float2* db, int j,
                                       float2 w1, float2 w2, float2 w3)
{
    float2 a0 = sa[PHX(j)], a1 = sa[PHX(j + 64)], a2 = sa[PHX(j + 128)], a3 = sa[PHX(j + 192)];
    float2 b0 = sb[PHX(j)], b1 = sb[PHX(j + 64)], b2 = sb[PHX(j + 128)], b3 = sb[PHX(j + 192)];
    bfly<NS, DIR>(a0, a1, a2, a3, da, j, w1, w2, w3);
    bfly<NS, DIR>(b0, b1, b2, b3, db, j, w1, w2, w3);
}

// dual 4-stage FFT-256; inputs in xa/xb, results end in xa/xb.
template<int DIR>
__device__ __forceinline__ void fft256_dual(float2* xa, float2* ya,
                                            float2* xb, float2* yb,
                                            int lane, const Tw& t)
{
    const float sg = (DIR < 0) ? 1.0f : -1.0f;
    float2 a1 = make_float2(t.a1.x, sg * t.a1.y), a2 = make_float2(t.a2.x, sg * t.a2.y),
           a3 = make_float2(t.a3.x, sg * t.a3.y);
    float2 bb1 = make_float2(t.b1.x, sg * t.b1.y), bb2 = make_float2(t.b2.x, sg * t.b2.y),
           bb3 = make_float2(t.b3.x, sg * t.b3.y);
    float2 cc1 = make_float2(t.c1.x, sg * t.c1.y), cc2 = make_float2(t.c2.x, sg * t.c2.y),
           cc3 = make_float2(t.c3.x, sg * t.c3.y);
    wave_sync();
    stage2<1,  DIR>(xa, xb, ya, yb, lane, a1, a1, a1);
    wave_sync();
    stage2<4,  DIR>(ya, yb, xa, xb, lane, a1, a2, a3);
    wave_sync();
    stage2<16, DIR>(xa, xb, ya, yb, lane, bb1, bb2, bb3);
    wave_sync();
    stage2<64, DIR>(ya, yb, xa, xb, lane, cc1, cc2, cc3);
    wave_sync();
}

// untangle Z = A + i*B (two real rows) and store packed rows
__device__ __forceinline__ void untangle_store(const float2* F, float* dstA, int lane)
{
    float4 oa, ob;
    if (lane == 0) {
        float2 Z0 = F[PHX(0)], Z128 = F[PHX(128)];
        float2 Z1 = F[PHX(1)], Zm = F[PHX(255)];
        float2 A1 = make_float2(0.5f * (Z1.x + Zm.x), 0.5f * (Z1.y - Zm.y));
        float2 Bd = make_float2(0.5f * (Z1.x - Zm.x), 0.5f * (Z1.y + Zm.y));
        float2 B1f = make_float2(Bd.y, -Bd.x);
        oa = make_float4(Z0.x, Z128.x, A1.x, A1.y);
        ob = make_float4(Z0.y, Z128.y, B1f.x, B1f.y);
    } else {
        int k0 = 2 * lane;
        float2 Zk0 = F[PHX(k0)],     Zm0 = F[PHX(256 - k0)];
        float2 Zk1 = F[PHX(k0 + 1)], Zm1 = F[PHX(255 - k0)];
        float2 A0 = make_float2(0.5f * (Zk0.x + Zm0.x), 0.5f * (Zk0.y - Zm0.y));
        float2 D0 = make_float2(0.5f * (Zk0.x - Zm0.x), 0.5f * (Zk0.y + Zm0.y));
        float2 Bf0 = make_float2(D0.y, -D0.x);
        float2 A1 = make_float2(0.5f * (Zk1.x + Zm1.x), 0.5f * (Zk1.y - Zm1.y));
        float2 D1 = make_float2(0.5f * (Zk1.x - Zm1.x), 0.5f * (Zk1.y + Zm1.y));
        float2 Bf1 = make_float2(D1.y, -D1.x);
        oa = make_float4(A0.x, A0.y, A1.x, A1.y);
        ob = make_float4(Bf0.x, Bf0.y, Bf1.x, Bf1.y);
    }
    *(float4*)(dstA + lane * 4)       = oa;
    *(float4*)(dstA + 256 + lane * 4) = ob;
}

// build V[k] = Ya[k] + i*Yb[k] from two packed rows into B0 (PHX layout)
__device__ __forceinline__ void tangle_load(float2* B0, const float* rowA,
                                            const float* rowB, int lane)
{
    float4 va = *(const float4*)(rowA + lane * 4);
    float4 vb = *(const float4*)(rowB + lane * 4);
    if (lane == 0) {
        B0[PHX(0)]   = make_float2(va.x, vb.x);
        B0[PHX(128)] = make_float2(va.y, vb.y);
        B0[PHX(1)]   = make_float2(va.z - vb.w, va.w + vb.z);
        B0[PHX(255)] = make_float2(va.z + vb.w, -va.w + vb.z);
    } else {
        int k0 = 2 * lane;
        B0[PHX(k0)]        = make_float2(va.x - vb.y, va.y + vb.x);
        B0[PHX(256 - k0)]  = make_float2(va.x + vb.y, -va.y + vb.x);
        B0[PHX(k0 + 1)]    = make_float2(va.z - vb.w, va.w + vb.z);
        B0[PHX(255 - k0)]  = make_float2(va.z + vb.w, -va.w + vb.z);
    }
}

// ---------------- K0: weight transpose -> wt[c][wf][h] float2 ----------------
__global__ __launch_bounds__(256) void k_wt(const float* __restrict__ wre,
                                            const float* __restrict__ wim,
                                            float2* __restrict__ wt)
{
    __shared__ float tr[32 * 129];
    __shared__ float ti[32 * 129];
    const int c  = blockIdx.x >> 3;
    const int h0 = (blockIdx.x & 7) * 32;
    const float* pr = wre + ((size_t)c * 256 + h0) * 129;
    const float* pi = wim + ((size_t)c * 256 + h0) * 129;
    for (int idx = threadIdx.x; idx < 32 * 129; idx += 256) {
        tr[idx] = pr[idx];
        ti[idx] = pi[idx];
    }
    __syncthreads();
    for (int idx = threadIdx.x; idx < 129 * 32; idx += 256) {
        int wf = idx >> 5, hl = idx & 31;
        wt[((size_t)c * 129 + wf) * 256 + h0 + hl] =
            make_float2(tr[hl * 129 + wf], ti[hl * 129 + wf]);
    }
}

// ---------------- K1: dual row-pair r2c per wave ----------------
__global__ __launch_bounds__(256) void k_rows_fwd(const float* __restrict__ x,
                                                  float* __restrict__ ws)
{
    __shared__ float2 buf[2][4][2][256];             // 32 KiB
    const int lane = threadIdx.x & 63;
    const int wv   = threadIdx.x >> 6;
    const int rp0  = blockIdx.x * 8 + wv * 2;        // two row pairs per wave
    const float* s0 = x + (size_t)rp0 * 512;

    Tw tw = make_tw(lane);

    float4 a0v = nt_load4(s0 + lane * 4);
    float4 b0v = nt_load4(s0 + 256 + lane * 4);
    float4 a1v = nt_load4(s0 + 512 + lane * 4);
    float4 b1v = nt_load4(s0 + 768 + lane * 4);

    float2* Xa = buf[0][wv][0]; float2* Ya = buf[1][wv][0];
    float2* Xb = buf[0][wv][1]; float2* Yb = buf[1][wv][1];
    Xa[PHX(4*lane + 0)] = make_float2(a0v.x, b0v.x);
    Xa[PHX(4*lane + 1)] = make_float2(a0v.y, b0v.y);
    Xa[PHX(4*lane + 2)] = make_float2(a0v.z, b0v.z);
    Xa[PHX(4*lane + 3)] = make_float2(a0v.w, b0v.w);
    Xb[PHX(4*lane + 0)] = make_float2(a1v.x, b1v.x);
    Xb[PHX(4*lane + 1)] = make_float2(a1v.y, b1v.y);
    Xb[PHX(4*lane + 2)] = make_float2(a1v.z, b1v.z);
    Xb[PHX(4*lane + 3)] = make_float2(a1v.w, b1v.w);

    fft256_dual<-1>(Xa, Ya, Xb, Yb, lane, tw);

    untangle_store(Xa, ws + (size_t)rp0 * 512, lane);
    untangle_store(Xb, ws + (size_t)(rp0 + 1) * 512, lane);
}

// ---------------- K2: register-column FFT + multiply + inverse ----------------
template<bool USEWT>
__global__ __launch_bounds__(256) void k_cols_r(float* __restrict__ ws,
                                                const float2* __restrict__ wt,
                                                const float* __restrict__ wre,
                                                const float* __restrict__ wim)
{
    __shared__ float2 A[16][273];                    // 34.9 KiB
    const int tid = threadIdx.x;
    const int l   = tid & 15;
    const int gk  = tid >> 4;
    const int nwg = gridDim.x;
    const int Lb  = (blockIdx.x & 7) * (nwg >> 3) + (blockIdx.x >> 3);
    const int pg  = Lb & 7;
    const int img = Lb >> 3;
    const int c   = img & 63;
    const int p0  = pg * 16;
    const int pair = p0 + gk;
    float* base = ws + (size_t)img * 65536;
    float2* Ag = A[gk];
    const float gn = 1.0f / 65536.0f;

    float2 W[16];
    if (USEWT) {
        const float2* wp = wt + ((size_t)c * 129 + pair) * 256;
#pragma unroll
        for (int k2 = 0; k2 < 16; ++k2) W[k2] = wp[l + 16 * k2];
    } else {
#pragma unroll
        for (int k2 = 0; k2 < 16; ++k2) {
            int ik = (c * 256 + l + 16 * k2) * 129 + pair;
            W[k2] = make_float2(wre[ik], wim[ik]);
        }
    }

#pragma unroll
    for (int i = 0; i < 8; ++i) {
        int idx = tid + 256 * i;
        int h = idx >> 3, q = idx & 7;
        float4 xv = *(const float4*)(base + h * 256 + p0 * 2 + q * 4);
        A[2*q    ][h] = make_float2(xv.x, xv.y);
        A[2*q + 1][h] = make_float2(xv.z, xv.w);
    }
    __syncthreads();

    float2 v[16];
#pragma unroll
    for (int n1 = 0; n1 < 16; ++n1) v[n1] = Ag[16 * n1 + l];

    gfft<-1>(v, Ag, l);

    if (pair == 0) {
        wave_sync();
#pragma unroll
        for (int k2 = 0; k2 < 16; ++k2) Ag[l + 16 * k2] = v[k2];
        wave_sync();
        float2 sm[16];
#pragma unroll
        for (int k2 = 0; k2 < 16; ++k2) {
            int m = (256 - (l + 16 * k2)) & 255;
            sm[k2] = Ag[m];
        }
#pragma unroll
        for (int k2 = 0; k2 < 16; ++k2) {
            int k = l + 16 * k2;
            int m = (256 - k) & 255;
            float2 Sk = v[k2], Sm = sm[k2];
            float2 S0   = make_float2(0.5f * (Sk.x + Sm.x), 0.5f * (Sk.y - Sm.y));
            float2 Dk   = make_float2(0.5f * (Sk.x - Sm.x), 0.5f * (Sk.y + Sm.y));
            float2 S128 = make_float2(Dk.y, -Dk.x);
            float2 wk0, wm0, wk128, wm128;
            if (USEWT) {
                const float2* w0r   = wt + ((size_t)c * 129 +   0) * 256;
                const float2* w128r = wt + ((size_t)c * 129 + 128) * 256;
                wk0 = W[k2];  wm0 = w0r[m];
                wk128 = w128r[k];  wm128 = w128r[m];
            } else {
                int ik = (c * 256 + k) * 129, im = (c * 256 + m) * 129;
                wk0   = make_float2(wre[ik], wim[ik]);
                wm0   = make_float2(wre[im], wim[im]);
                wk128 = make_float2(wre[ik + 128], wim[ik + 128]);
                wm128 = make_float2(wre[im + 128], wim[im + 128]);
            }
            float2 A0   = make_float2(0.5f * gn * (wk0.x + wm0.x),
                                      0.5f * gn * (wk0.y - wm0.y));
            float2 A128 = make_float2(0.5f * gn * (wk128.x + wm128.x),
                                      0.5f * gn * (wk128.y - wm128.y));
            float2 y0 = cmulf(S0, A0);
            float2 y1 = cmulf(S128, A128);
            v[k2] = make_float2(y0.x - y1.y, y0.y + y1.x);
        }
    } else {
#pragma unroll
        for (int k2 = 0; k2 < 16; ++k2)
            v[k2] = cmulf(v[k2], make_float2(gn * W[k2].x, gn * W[k2].y));
    }

    gfft<+1>(v, Ag, l);

    wave_sync();
#pragma unroll
    for (int k2 = 0; k2 < 16; ++k2) Ag[l + 16 * k2] = v[k2];
    __syncthreads();
#pragma unroll
    for (int i = 0; i < 8; ++i) {
        int idx = tid + 256 * i;
        int h = idx >> 3, q = idx & 7;
        float2 a = A[2*q    ][h];
        float2 b = A[2*q + 1][h];
        *(float4*)(base + h * 256 + p0 * 2 + q * 4) = make_float4(a.x, a.y, b.x, b.y);
    }
}

// ---------------- K3: dual row-pair c2r per wave, in place ----------------
__global__ __launch_bounds__(256) void k_rows_inv(float* __restrict__ ws)
{
    __shared__ float2 buf[2][4][2][256];             // 32 KiB
    const int lane = threadIdx.x & 63;
    const int wv   = threadIdx.x >> 6;
    const int rp0  = blockIdx.x * 8 + wv * 2;
    float* r0 = ws + (size_t)rp0 * 512;

    Tw tw = make_tw(lane);

    float2* Xa = buf[0][wv][0]; float2* Ya = buf[1][wv][0];
    float2* Xb = buf[0][wv][1]; float2* Yb = buf[1][wv][1];
    tangle_load(Xa, r0,       r0 + 256, lane);
    tangle_load(Xb, r0 + 512, r0 + 768, lane);

    fft256_dual<+1>(Xa, Ya, Xb, Yb, lane, tw);

    {
        const float2* F = Xa;
        float2 f0 = F[PHX(4*lane)], f1 = F[PHX(4*lane + 1)];
        float2 f2 = F[PHX(4*lane + 2)], f3 = F[PHX(4*lane + 3)];
        nt_store4(r0 + lane * 4,       make_float4(f0.x, f1.x, f2.x, f3.x));
        nt_store4(r0 + 256 + lane * 4, make_float4(f0.y, f1.y, f2.y, f3.y));
    }
    {
        const float2* F = Xb;
        float2 f0 = F[PHX(4*lane)], f1 = F[PHX(4*lane + 1)];
        float2 f2 = F[PHX(4*lane + 2)], f3 = F[PHX(4*lane + 3)];
        nt_store4(r0 + 512 + lane * 4, make_float4(f0.x, f1.x, f2.x, f3.x));
        nt_store4(r0 + 768 + lane * 4, make_float4(f0.y, f1.y, f2.y, f3.y));
    }
}

extern "C" void kernel_launch(void* const* d_in, const int* in_sizes, int n_in,
                              void* d_out, int out_size, void* d_ws, size_t ws_size,
                              hipStream_t stream)
{
    (void)in_sizes; (void)n_in; (void)out_size;
    const float* x   = (const float*)d_in[0];
    const float* wre = (const float*)d_in[1];
    const float* wim = (const float*)d_in[2];
    float* out = (float*)d_out;
    float2* wt = (float2*)d_ws;

    const size_t wt_bytes = (size_t)64 * 129 * 256 * sizeof(float2);  // 16.9 MB
    const bool use_wt = (ws_size >= wt_bytes);

    if (use_wt) {
        k_wt<<<dim3(512), dim3(256), 0, stream>>>(wre, wim, wt);
    }
    // B*C*H/2 = 131072 row pairs, 8 per block (2 per wave)
    k_rows_fwd<<<dim3(16384), dim3(256), 0, stream>>>(x, out);
    // 1024 images x 8 pair-groups (16 pairs per block)
    if (use_wt)
        k_cols_r<true ><<<dim3(8192), dim3(256), 0, stream>>>(out, wt, wre, wim);
    else
        k_cols_r<false><<<dim3(8192), dim3(256), 0, stream>>>(out, wt, wre, wim);
    k_rows_inv<<<dim3(16384), dim3(256), 0, stream>>>(out);
}